// Round 4
// baseline (386.676 us; speedup 1.0000x reference)
//
#include <hip/hip_runtime.h>
#include <math.h>

#define TOKENS 4096
#define DMODEL 768
#define NHEADS 12
#define HDIM   64
#define QKV_N  2304          // 3*DMODEL
#define ATTN_SCALE 0.125f    // HDIM^-0.5
// fold log2(e) into Q so softmax uses v_exp_f32 (2^x) directly
#define QSCALE_LOG2E (0.125f * 1.44269504088896340736f)

typedef __attribute__((ext_vector_type(8))) short bf16x8;   // 8 bf16 = 4 VGPRs
typedef __attribute__((ext_vector_type(4))) float floatx4;

__device__ __forceinline__ ushort f2bf(float f) {
    union { float f; unsigned u; } cv; cv.f = f;
    unsigned u = cv.u;
    u += 0x7fffu + ((u >> 16) & 1u);   // round-to-nearest-even
    return (ushort)(u >> 16);
}

// pack two fp32 -> two bf16 (RNE) in one dword via v_cvt_pk_bf16_f32
__device__ __forceinline__ unsigned cvt_pk_bf16(float a, float b) {
    unsigned r;
    asm("v_cvt_pk_bf16_f32 %0, %1, %2" : "=v"(r) : "v"(a), "v"(b));
    return r;
}

// async 16B global->LDS (lane i lands at ldsbase + i*16)
__device__ __forceinline__ void gl2lds16(const ushort* g, ushort* l) {
    __builtin_amdgcn_global_load_lds(
        (const __attribute__((address_space(1))) void*)g,
        (__attribute__((address_space(3))) void*)l, 16, 0, 0);
}

// fragment read (64-ushort rows): logical chunk c of row r at phys (c ^ (r&7))
__device__ __forceinline__ bf16x8 frag(const ushort* ls, int row, int chunk) {
    return *(const bf16x8*)(ls + row * 64 + ((chunk ^ (row & 7)) * 8));
}

// ---------------------------------------------------------------------------
// fp32 -> bf16 elementwise (x)
// ---------------------------------------------------------------------------
__global__ __launch_bounds__(256) void cvt_bf16_kernel(
    const float* __restrict__ in, ushort* __restrict__ out, int n4)
{
    const int i = blockIdx.x * 256 + threadIdx.x;
    if (i < n4) {
        const float4 v = ((const float4*)in)[i];
        ushort4 h;
        h.x = f2bf(v.x); h.y = f2bf(v.y); h.z = f2bf(v.z); h.w = f2bf(v.w);
        ((ushort4*)out)[i] = h;
    }
}

// ---------------------------------------------------------------------------
// fp32 [R][C] -> bf16 [C][R] transpose-convert (weights -> B^T operand layout)
// ---------------------------------------------------------------------------
__global__ __launch_bounds__(256) void transpose_cvt_kernel(
    const float* __restrict__ in, ushort* __restrict__ out, int R, int C)
{
    __shared__ ushort tile[32][33];
    const int tx  = threadIdx.x & 31;
    const int ty8 = threadIdx.x >> 5;           // 0..7
    const int c0 = blockIdx.x * 32;
    const int r0 = blockIdx.y * 32;
    #pragma unroll
    for (int p = 0; p < 4; ++p) {
        const int r = ty8 + p * 8;
        tile[r][tx] = f2bf(in[(size_t)(r0 + r) * C + c0 + tx]);
    }
    __syncthreads();
    #pragma unroll
    for (int p = 0; p < 4; ++p) {
        const int c = ty8 + p * 8;
        out[(size_t)(c0 + c) * R + r0 + tx] = tile[tx][c];
    }
}

// ---------------------------------------------------------------------------
// MFMA GEMM body (m97 recipe): 128 x (NT*32) tile, BK=64, 4 waves 2x2.
// ---------------------------------------------------------------------------
template<int NT>
__device__ __forceinline__ void gemm_body_async(
    const ushort* __restrict__ A, const ushort* __restrict__ Bt, int K,
    int m0, int n0, floatx4 acc[4][NT], ushort* ls)
{
    ushort* lsA = ls;
    ushort* lsB = ls + 8192;

    const int tid  = threadIdx.x;
    const int lane = tid & 63;
    const int wave = tid >> 6;
    const int wm = wave >> 1, wn = wave & 1;
    const int quad = lane >> 4, l16 = lane & 15;

    const int lrow = lane >> 3;          // 0..7
    const int csw  = ((lane & 7) ^ lrow) * 8;   // swizzled global chunk (ushorts)

    const ushort* gA = A  + (size_t)(m0 + wave * 32 + lrow) * K + csw;
    const ushort* gB = Bt + (size_t)(n0 + wave * NT * 8 + lrow) * K + csw;
    ushort* lA = lsA + (wave * 32) * 64;
    ushort* lB = lsB + (wave * NT * 8) * 64;

    for (int k0 = 0; k0 < K; k0 += 64) {
        __syncthreads();
        #pragma unroll
        for (int p = 0; p < 4; ++p)
            gl2lds16(gA + (size_t)p * 8 * K + k0, lA + p * 8 * 64);
        #pragma unroll
        for (int p = 0; p < NT; ++p)
            gl2lds16(gB + (size_t)p * 8 * K + k0, lB + p * 8 * 64);
        __syncthreads();

        #pragma unroll
        for (int ks = 0; ks < 2; ++ks) {
            bf16x8 af[4], bfr[NT];
            #pragma unroll
            for (int mt = 0; mt < 4; ++mt)
                af[mt] = frag(lsA, wm * 64 + mt * 16 + l16, ks * 4 + quad);
            #pragma unroll
            for (int nt = 0; nt < NT; ++nt)
                bfr[nt] = frag(lsB, wn * NT * 16 + nt * 16 + l16, ks * 4 + quad);
            #pragma unroll
            for (int mt = 0; mt < 4; ++mt)
                #pragma unroll
                for (int nt = 0; nt < NT; ++nt)
                    acc[mt][nt] = __builtin_amdgcn_mfma_f32_16x16x32_bf16(
                        af[mt], bfr[nt], acc[mt][nt], 0, 0, 0);
        }
    }
}

// ---------------------------------------------------------------------------
// qkv GEMM: 128x128 tiles. Epilogue re-tiles through LDS (stride 136).
// ---------------------------------------------------------------------------
__global__ __launch_bounds__(256) void gemm_qkv_mfma(
    const ushort* __restrict__ Xb, const ushort* __restrict__ Wt,
    ushort* __restrict__ Qb, ushort* __restrict__ Kb, ushort* __restrict__ Vt)
{
    __shared__ __align__(16) ushort ls[16384];   // 32 KB: GEMM tiles + retile
    const int m0 = blockIdx.y * 128;
    const int n0 = blockIdx.x * 128;

    floatx4 acc[4][4] = {};
    gemm_body_async<4>(Xb, Wt, DMODEL, m0, n0, acc, ls);

    const int tid  = threadIdx.x;
    const int lane = tid & 63;
    const int wave = tid >> 6;
    const int wm = wave >> 1, wn = wave & 1;
    const int quad = lane >> 4, l16 = lane & 15;

    if (n0 < 2 * DMODEL) {
        // ---- Q or K: two passes over 64-row halves ----
        const float scale = (n0 < DMODEL) ? QSCALE_LOG2E : 1.0f;
        ushort* outp = (n0 < DMODEL) ? Qb : Kb;
        const int colg = (n0 < DMODEL) ? n0 : n0 - DMODEL;
        #pragma unroll
        for (int p = 0; p < 2; ++p) {
            __syncthreads();
            if (wm == p) {
                #pragma unroll
                for (int mt = 0; mt < 4; ++mt)
                    #pragma unroll
                    for (int nt = 0; nt < 4; ++nt) {
                        const int row = mt * 16 + quad * 4;
                        const int col = wn * 64 + nt * 16 + l16;
                        #pragma unroll
                        for (int r = 0; r < 4; ++r)
                            ls[(row + r) * 136 + col] = f2bf(acc[mt][nt][r] * scale);
                    }
            }
            __syncthreads();
            #pragma unroll
            for (int p2 = 0; p2 < 4; ++p2) {
                const int row = (tid >> 4) + p2 * 16;
                const int c8  = (tid & 15) * 8;
                *(uint4*)(outp + (size_t)(m0 + p * 64 + row) * DMODEL + colg + c8) =
                    *(const uint4*)(ls + row * 136 + c8);
            }
        }
    } else {
        // ---- V transposed: two passes over 64-hd halves ----
        const int hd0 = n0 - 2 * DMODEL;
        #pragma unroll
        for (int p = 0; p < 2; ++p) {
            __syncthreads();
            if (wn == p) {
                #pragma unroll
                for (int mt = 0; mt < 4; ++mt)
                    #pragma unroll
                    for (int nt = 0; nt < 4; ++nt) {
                        const int hd  = nt * 16 + l16;
                        const int tok = wm * 64 + mt * 16 + quad * 4;
                        #pragma unroll
                        for (int r = 0; r < 4; ++r)
                            ls[hd * 136 + tok + r] = f2bf(acc[mt][nt][r]);
                    }
            }
            __syncthreads();
            #pragma unroll
            for (int p2 = 0; p2 < 4; ++p2) {
                const int row = (tid >> 4) + p2 * 16;    // local hd
                const int c8  = (tid & 15) * 8;          // token chunk
                *(uint4*)(Vt + (size_t)(hd0 + p * 64 + row) * TOKENS + m0 + c8) =
                    *(const uint4*)(ls + row * 136 + c8);
            }
        }
    }
}

// ---------------------------------------------------------------------------
// proj GEMM: 128x64 tiles (grid 384), direct fp32 stores (full 64B sectors).
// ---------------------------------------------------------------------------
__global__ __launch_bounds__(256) void gemm_proj_mfma(
    const ushort* __restrict__ Ab, const ushort* __restrict__ Wt,
    const float* __restrict__ bias, float* __restrict__ out)
{
    __shared__ __align__(16) ushort ls[12288];   // 16 KB A + 8 KB B
    const int m0 = blockIdx.y * 128;
    const int n0 = blockIdx.x * 64;

    floatx4 acc[4][2] = {};
    gemm_body_async<2>(Ab, Wt, DMODEL, m0, n0, acc, ls);

    const int lane = threadIdx.x & 63;
    const int wave = threadIdx.x >> 6;
    const int wm = wave >> 1, wn = wave & 1;
    const int quad = lane >> 4, l16 = lane & 15;
    const int row0 = m0 + wm * 64 + quad * 4;
    const int col0 = n0 + wn * 32;

    #pragma unroll
    for (int nt = 0; nt < 2; ++nt) {
        const int col = col0 + nt * 16 + l16;
        const float bv = bias[col];
        #pragma unroll
        for (int mt = 0; mt < 4; ++mt)
            #pragma unroll
            for (int r = 0; r < 4; ++r)
                out[(size_t)(row0 + mt * 16 + r) * DMODEL + col] =
                    acc[mt][nt][r] + bv;
    }
}

// ---------------------------------------------------------------------------
// MFMA flash attention v5 — BARRIER-FREE register streaming.
//
// r1-r3 post-mortem: three different structures all ~1130-1440 cy per 64-key
// unit with every pipe <=30% busy. Invariant = the per-chunk __syncthreads
// (vmcnt(0)+lgkmcnt(0) drain): it phase-locks all waves (QK/exp/PV stall on
// the same pipe simultaneously) and blocks cross-iteration load/compute
// overlap. v5 removes LDS/DMA/barriers from the main loop entirely:
//   - K fragments: direct global->VGPR (as r3).
//   - V fragments: direct global->VGPR. In Vt [hd][tok] layout the B-operand
//     read is 2x8B per lane, 16 rows x 64B contiguous per fragment (full
//     sectors, L1/L2-resident). Permuted k-slot mapping as before: slot
//     half 0 <- tokens +quad*4, half 1 <- tokens +16+quad*4.
//   - No __syncthreads in the loop: compiler hoists next-chunk loads over
//     current-chunk MFMAs with counted s_waitcnt; waves drift out of phase
//     -> MFMA/VALU/VMEM pipes overlap across waves.
// LDS = 17 KB epilogue reduction buffer only. 2x2 wave split (32q x 64k),
// grid 768 = 3 blocks/CU, 12 waves/CU.
// ---------------------------------------------------------------------------
__global__ __launch_bounds__(256, 3) void attn_mfma_kernel(
    const ushort* __restrict__ Qb, const ushort* __restrict__ Kb,
    const ushort* __restrict__ Vt, ushort* __restrict__ attn_out)
{
    __shared__ float redbuf[2 * 32 * 66 + 64];   // epilogue only (~17 KB)

    const int tid  = threadIdx.x;
    const int wave = tid >> 6;
    const int qg   = wave >> 1;          // query group (32 q each)
    const int kg   = wave & 1;           // key group (64 k each)
    const int lane = tid & 63;
    const int quad = lane >> 4;
    const int l16  = lane & 15;
    const int h    = blockIdx.y;
    const int i0   = blockIdx.x * 64;

    // Q fragments: 2 q-tiles (queries i0 + qg*32 + jt*16 + l16)
    bf16x8 qf[2][2];
    #pragma unroll
    for (int jt = 0; jt < 2; ++jt) {
        const ushort* qb = Qb + (size_t)(i0 + qg * 32 + jt * 16 + l16) * DMODEL + h * HDIM;
        qf[jt][0] = *(const bf16x8*)(qb + quad * 8);
        qf[jt][1] = *(const bf16x8*)(qb + 32 + quad * 8);
    }

    bf16x8 ones;
    #pragma unroll
    for (int i = 0; i < 8; ++i) ones[i] = (short)0x3F80;   // bf16 1.0

    floatx4 O[2][4] = {};    // [q-tile][d-tile], partial over this wave's 64 keys
    floatx4 Ol[2]   = {};    // [q-tile] partial row-sums

    // K fragment base: key = kg*64 + (g*32 + kt2*16) + l16, hd = quad*8 (+kh*32)
    const ushort* gKf = Kb + (size_t)(kg * 64 + l16) * DMODEL + h * HDIM + quad * 8;
    // V fragment base: d-row = l16 (+nt*16), tokens kg*64 + quad*4 (+g*32, +16)
    const ushort* gVf = Vt + (size_t)(h * HDIM + l16) * TOKENS + kg * 64 + quad * 4;

    for (int j0 = 0; j0 < TOKENS; j0 += 128) {
        // ---- issue ALL loads for this 128-key chunk up front ----
        bf16x8 af[2][2][2];          // [g][kt2][kh]
        #pragma unroll
        for (int g = 0; g < 2; ++g)
            #pragma unroll
            for (int kt2 = 0; kt2 < 2; ++kt2)
                #pragma unroll
                for (int kh = 0; kh < 2; ++kh)
                    af[g][kt2][kh] = *(const bf16x8*)(
                        gKf + (size_t)(j0 + g * 32 + kt2 * 16) * DMODEL + kh * 32);

        union { bf16x8 v; uint2 d[2]; } vu[2][4];    // [g][nt]
        #pragma unroll
        for (int g = 0; g < 2; ++g)
            #pragma unroll
            for (int nt = 0; nt < 4; ++nt) {
                const ushort* vb = gVf + (size_t)(nt * 16) * TOKENS + j0 + g * 32;
                vu[g][nt].d[0] = *(const uint2*)(vb);        // tokens +quad*4+0..3
                vu[g][nt].d[1] = *(const uint2*)(vb + 16);   // tokens +16+quad*4+0..3
            }

        // ---- two 32-key stages: QK^T -> exp2/pack -> l,O mfma ----
        #pragma unroll
        for (int g = 0; g < 2; ++g) {
            floatx4 sv[2][2];
            #pragma unroll
            for (int jt = 0; jt < 2; ++jt)
                #pragma unroll
                for (int kt2 = 0; kt2 < 2; ++kt2) {
                    floatx4 s = {0.f, 0.f, 0.f, 0.f};
                    s = __builtin_amdgcn_mfma_f32_16x16x32_bf16(af[g][kt2][0], qf[jt][0], s, 0, 0, 0);
                    s = __builtin_amdgcn_mfma_f32_16x16x32_bf16(af[g][kt2][1], qf[jt][1], s, 0, 0, 0);
                    sv[jt][kt2] = s;
                }

            bf16x8 pa[2];
            #pragma unroll
            for (int jt = 0; jt < 2; ++jt) {
                union { bf16x8 v; unsigned u[4]; } pu;
                #pragma unroll
                for (int h2 = 0; h2 < 2; ++h2) {
                    const float p0 = __builtin_amdgcn_exp2f(sv[jt][h2][0]);
                    const float p1 = __builtin_amdgcn_exp2f(sv[jt][h2][1]);
                    const float p2 = __builtin_amdgcn_exp2f(sv[jt][h2][2]);
                    const float p3 = __builtin_amdgcn_exp2f(sv[jt][h2][3]);
                    pu.u[h2 * 2]     = cvt_pk_bf16(p0, p1);
                    pu.u[h2 * 2 + 1] = cvt_pk_bf16(p2, p3);
                }
                pa[jt] = pu.v;
                Ol[jt] = __builtin_amdgcn_mfma_f32_16x16x32_bf16(pa[jt], ones, Ol[jt], 0, 0, 0);
            }

            #pragma unroll
            for (int nt = 0; nt < 4; ++nt)
                #pragma unroll
                for (int jt = 0; jt < 2; ++jt)
                    O[jt][nt] = __builtin_amdgcn_mfma_f32_16x16x32_bf16(
                        pa[jt], vu[g][nt].v, O[jt][nt], 0, 0, 0);
        }
    }

    // ---- cross-wave (kg pair) reduction + store ----
    __syncthreads();
    float* Of  = redbuf;                   // 2 regions of [32][66] f32
    float* Olf = redbuf + 2 * 32 * 66;     // 2 x [32] f32
    if (kg == 1) {
        float* o = Of + qg * 32 * 66;
        #pragma unroll
        for (int jt = 0; jt < 2; ++jt) {
            #pragma unroll
            for (int nt = 0; nt < 4; ++nt)
                #pragma unroll
                for (int r = 0; r < 4; ++r)
                    o[(jt * 16 + quad * 4 + r) * 66 + nt * 16 + l16] = O[jt][nt][r];
            if (l16 == 0) {
                #pragma unroll
                for (int r = 0; r < 4; ++r)
                    Olf[qg * 32 + jt * 16 + quad * 4 + r] = Ol[jt][r];
            }
        }
    }
    __syncthreads();
    if (kg == 0) {
        #pragma unroll
        for (int jt = 0; jt < 2; ++jt) {
            const int qr = jt * 16 + quad * 4;
            float linv[4];
            #pragma unroll
            for (int r = 0; r < 4; ++r) {
                const float l = Ol[jt][r] + Olf[qg * 32 + qr + r];
                linv[r] = __builtin_amdgcn_rcpf(l);
            }
            #pragma unroll
            for (int nt = 0; nt < 4; ++nt) {
                const int d = h * HDIM + nt * 16 + l16;
                #pragma unroll
                for (int r = 0; r < 4; ++r) {
                    const float o = O[jt][nt][r]
                        + Of[qg * 32 * 66 + (qr + r) * 66 + nt * 16 + l16];
                    attn_out[(size_t)(i0 + qg * 32 + qr + r) * DMODEL + d] =
                        f2bf(o * linv[r]);
                }
            }
        }
    }
}

// ---------------------------------------------------------------------------
extern "C" void kernel_launch(void* const* d_in, const int* in_sizes, int n_in,
                              void* d_out, int out_size, void* d_ws, size_t ws_size,
                              hipStream_t stream)
{
    const float* x     = (const float*)d_in[0];
    const float* Wqkv  = (const float*)d_in[1];
    const float* Wproj = (const float*)d_in[2];
    const float* bproj = (const float*)d_in[3];
    float* out = (float*)d_out;

    ushort* Xb     = (ushort*)d_ws;                          // [4096][768]
    ushort* WqkvT  = Xb    + (size_t)TOKENS * DMODEL;        // [2304][768]
    ushort* WprojT = WqkvT + (size_t)QKV_N * DMODEL;         // [768][768]
    ushort* Qb     = WprojT + (size_t)DMODEL * DMODEL;       // [4096][768]
    ushort* Kb     = Qb    + (size_t)TOKENS * DMODEL;        // [4096][768]
    ushort* Vt     = Kb    + (size_t)TOKENS * DMODEL;        // [768][4096]
    ushort* attn   = Vt    + (size_t)TOKENS * DMODEL;        // [4096][768]

    cvt_bf16_kernel<<<dim3(TOKENS * DMODEL / 4 / 256), 256, 0, stream>>>(
        x, Xb, TOKENS * DMODEL / 4);
    transpose_cvt_kernel<<<dim3(QKV_N / 32, DMODEL / 32), 256, 0, stream>>>(
        Wqkv, WqkvT, DMODEL, QKV_N);
    transpose_cvt_kernel<<<dim3(DMODEL / 32, DMODEL / 32), 256, 0, stream>>>(
        Wproj, WprojT, DMODEL, DMODEL);

    gemm_qkv_mfma<<<dim3(QKV_N / 128, TOKENS / 128), 256, 0, stream>>>(
        Xb, WqkvT, Qb, Kb, Vt);

    attn_mfma_kernel<<<dim3(TOKENS / 64, NHEADS), 256, 0, stream>>>(
        Qb, Kb, Vt, attn);

    gemm_proj_mfma<<<dim3(DMODEL / 64, TOKENS / 128), 256, 0, stream>>>(
        attn, WprojT, bproj, out);
}

// Round 5
// 208.311 us; speedup vs baseline: 1.8562x; 1.8562x over previous
//
#include <hip/hip_runtime.h>
#include <math.h>

#define TOKENS 4096
#define DMODEL 768
#define NHEADS 12
#define HDIM   64
#define QKV_N  2304          // 3*DMODEL
#define ATTN_SCALE 0.125f    // HDIM^-0.5
// fold log2(e) into Q so softmax uses v_exp_f32 (2^x) directly
#define QSCALE_LOG2E (0.125f * 1.44269504088896340736f)

typedef __attribute__((ext_vector_type(8))) short bf16x8;   // 8 bf16 = 4 VGPRs
typedef __attribute__((ext_vector_type(4))) float floatx4;

__device__ __forceinline__ ushort f2bf(float f) {
    union { float f; unsigned u; } cv; cv.f = f;
    unsigned u = cv.u;
    u += 0x7fffu + ((u >> 16) & 1u);   // round-to-nearest-even
    return (ushort)(u >> 16);
}

// pack two fp32 -> two bf16 (RNE) in one dword via v_cvt_pk_bf16_f32
__device__ __forceinline__ unsigned cvt_pk_bf16(float a, float b) {
    unsigned r;
    asm("v_cvt_pk_bf16_f32 %0, %1, %2" : "=v"(r) : "v"(a), "v"(b));
    return r;
}

// async 16B global->LDS (lane i lands at ldsbase + i*16)
__device__ __forceinline__ void gl2lds16(const ushort* g, ushort* l) {
    __builtin_amdgcn_global_load_lds(
        (const __attribute__((address_space(1))) void*)g,
        (__attribute__((address_space(3))) void*)l, 16, 0, 0);
}

// fragment read (64-ushort rows): logical chunk c of row r at phys (c ^ (r&7))
__device__ __forceinline__ bf16x8 frag(const ushort* ls, int row, int chunk) {
    return *(const bf16x8*)(ls + row * 64 + ((chunk ^ (row & 7)) * 8));
}

// ---------------------------------------------------------------------------
// fp32 -> bf16 elementwise (x)
// ---------------------------------------------------------------------------
__global__ __launch_bounds__(256) void cvt_bf16_kernel(
    const float* __restrict__ in, ushort* __restrict__ out, int n4)
{
    const int i = blockIdx.x * 256 + threadIdx.x;
    if (i < n4) {
        const float4 v = ((const float4*)in)[i];
        ushort4 h;
        h.x = f2bf(v.x); h.y = f2bf(v.y); h.z = f2bf(v.z); h.w = f2bf(v.w);
        ((ushort4*)out)[i] = h;
    }
}

// ---------------------------------------------------------------------------
// fp32 [R][C] -> bf16 [C][R] transpose-convert (weights -> B^T operand layout)
// ---------------------------------------------------------------------------
__global__ __launch_bounds__(256) void transpose_cvt_kernel(
    const float* __restrict__ in, ushort* __restrict__ out, int R, int C)
{
    __shared__ ushort tile[32][33];
    const int tx  = threadIdx.x & 31;
    const int ty8 = threadIdx.x >> 5;           // 0..7
    const int c0 = blockIdx.x * 32;
    const int r0 = blockIdx.y * 32;
    #pragma unroll
    for (int p = 0; p < 4; ++p) {
        const int r = ty8 + p * 8;
        tile[r][tx] = f2bf(in[(size_t)(r0 + r) * C + c0 + tx]);
    }
    __syncthreads();
    #pragma unroll
    for (int p = 0; p < 4; ++p) {
        const int c = ty8 + p * 8;
        out[(size_t)(c0 + c) * R + r0 + tx] = tile[tx][c];
    }
}

// ---------------------------------------------------------------------------
// MFMA GEMM body (m97 recipe): 128 x (NT*32) tile, BK=64, 4 waves 2x2.
// ---------------------------------------------------------------------------
template<int NT>
__device__ __forceinline__ void gemm_body_async(
    const ushort* __restrict__ A, const ushort* __restrict__ Bt, int K,
    int m0, int n0, floatx4 acc[4][NT], ushort* ls)
{
    ushort* lsA = ls;
    ushort* lsB = ls + 8192;

    const int tid  = threadIdx.x;
    const int lane = tid & 63;
    const int wave = tid >> 6;
    const int wm = wave >> 1, wn = wave & 1;
    const int quad = lane >> 4, l16 = lane & 15;

    const int lrow = lane >> 3;          // 0..7
    const int csw  = ((lane & 7) ^ lrow) * 8;   // swizzled global chunk (ushorts)

    const ushort* gA = A  + (size_t)(m0 + wave * 32 + lrow) * K + csw;
    const ushort* gB = Bt + (size_t)(n0 + wave * NT * 8 + lrow) * K + csw;
    ushort* lA = lsA + (wave * 32) * 64;
    ushort* lB = lsB + (wave * NT * 8) * 64;

    for (int k0 = 0; k0 < K; k0 += 64) {
        __syncthreads();
        #pragma unroll
        for (int p = 0; p < 4; ++p)
            gl2lds16(gA + (size_t)p * 8 * K + k0, lA + p * 8 * 64);
        #pragma unroll
        for (int p = 0; p < NT; ++p)
            gl2lds16(gB + (size_t)p * 8 * K + k0, lB + p * 8 * 64);
        __syncthreads();

        #pragma unroll
        for (int ks = 0; ks < 2; ++ks) {
            bf16x8 af[4], bfr[NT];
            #pragma unroll
            for (int mt = 0; mt < 4; ++mt)
                af[mt] = frag(lsA, wm * 64 + mt * 16 + l16, ks * 4 + quad);
            #pragma unroll
            for (int nt = 0; nt < NT; ++nt)
                bfr[nt] = frag(lsB, wn * NT * 16 + nt * 16 + l16, ks * 4 + quad);
            #pragma unroll
            for (int mt = 0; mt < 4; ++mt)
                #pragma unroll
                for (int nt = 0; nt < NT; ++nt)
                    acc[mt][nt] = __builtin_amdgcn_mfma_f32_16x16x32_bf16(
                        af[mt], bfr[nt], acc[mt][nt], 0, 0, 0);
        }
    }
}

// ---------------------------------------------------------------------------
// qkv GEMM: 128x128 tiles. Epilogue re-tiles through LDS (stride 136).
// ---------------------------------------------------------------------------
__global__ __launch_bounds__(256) void gemm_qkv_mfma(
    const ushort* __restrict__ Xb, const ushort* __restrict__ Wt,
    ushort* __restrict__ Qb, ushort* __restrict__ Kb, ushort* __restrict__ Vt)
{
    __shared__ __align__(16) ushort ls[16384];   // 32 KB: GEMM tiles + retile
    const int m0 = blockIdx.y * 128;
    const int n0 = blockIdx.x * 128;

    floatx4 acc[4][4] = {};
    gemm_body_async<4>(Xb, Wt, DMODEL, m0, n0, acc, ls);

    const int tid  = threadIdx.x;
    const int lane = tid & 63;
    const int wave = tid >> 6;
    const int wm = wave >> 1, wn = wave & 1;
    const int quad = lane >> 4, l16 = lane & 15;

    if (n0 < 2 * DMODEL) {
        // ---- Q or K: two passes over 64-row halves ----
        const float scale = (n0 < DMODEL) ? QSCALE_LOG2E : 1.0f;
        ushort* outp = (n0 < DMODEL) ? Qb : Kb;
        const int colg = (n0 < DMODEL) ? n0 : n0 - DMODEL;
        #pragma unroll
        for (int p = 0; p < 2; ++p) {
            __syncthreads();
            if (wm == p) {
                #pragma unroll
                for (int mt = 0; mt < 4; ++mt)
                    #pragma unroll
                    for (int nt = 0; nt < 4; ++nt) {
                        const int row = mt * 16 + quad * 4;
                        const int col = wn * 64 + nt * 16 + l16;
                        #pragma unroll
                        for (int r = 0; r < 4; ++r)
                            ls[(row + r) * 136 + col] = f2bf(acc[mt][nt][r] * scale);
                    }
            }
            __syncthreads();
            #pragma unroll
            for (int p2 = 0; p2 < 4; ++p2) {
                const int row = (tid >> 4) + p2 * 16;
                const int c8  = (tid & 15) * 8;
                *(uint4*)(outp + (size_t)(m0 + p * 64 + row) * DMODEL + colg + c8) =
                    *(const uint4*)(ls + row * 136 + c8);
            }
        }
    } else {
        // ---- V transposed: two passes over 64-hd halves ----
        const int hd0 = n0 - 2 * DMODEL;
        #pragma unroll
        for (int p = 0; p < 2; ++p) {
            __syncthreads();
            if (wn == p) {
                #pragma unroll
                for (int mt = 0; mt < 4; ++mt)
                    #pragma unroll
                    for (int nt = 0; nt < 4; ++nt) {
                        const int hd  = nt * 16 + l16;
                        const int tok = wm * 64 + mt * 16 + quad * 4;
                        #pragma unroll
                        for (int r = 0; r < 4; ++r)
                            ls[hd * 136 + tok + r] = f2bf(acc[mt][nt][r]);
                    }
            }
            __syncthreads();
            #pragma unroll
            for (int p2 = 0; p2 < 4; ++p2) {
                const int row = (tid >> 4) + p2 * 16;    // local hd
                const int c8  = (tid & 15) * 8;          // token chunk
                *(uint4*)(Vt + (size_t)(hd0 + p * 64 + row) * TOKENS + m0 + c8) =
                    *(const uint4*)(ls + row * 136 + c8);
            }
        }
    }
}

// ---------------------------------------------------------------------------
// proj GEMM: 128x64 tiles (grid 384), direct fp32 stores (full 64B sectors).
// ---------------------------------------------------------------------------
__global__ __launch_bounds__(256) void gemm_proj_mfma(
    const ushort* __restrict__ Ab, const ushort* __restrict__ Wt,
    const float* __restrict__ bias, float* __restrict__ out)
{
    __shared__ __align__(16) ushort ls[12288];   // 16 KB A + 8 KB B
    const int m0 = blockIdx.y * 128;
    const int n0 = blockIdx.x * 64;

    floatx4 acc[4][2] = {};
    gemm_body_async<2>(Ab, Wt, DMODEL, m0, n0, acc, ls);

    const int lane = threadIdx.x & 63;
    const int wave = threadIdx.x >> 6;
    const int wm = wave >> 1, wn = wave & 1;
    const int quad = lane >> 4, l16 = lane & 15;
    const int row0 = m0 + wm * 64 + quad * 4;
    const int col0 = n0 + wn * 32;

    #pragma unroll
    for (int nt = 0; nt < 2; ++nt) {
        const int col = col0 + nt * 16 + l16;
        const float bv = bias[col];
        #pragma unroll
        for (int mt = 0; mt < 4; ++mt)
            #pragma unroll
            for (int r = 0; r < 4; ++r)
                out[(size_t)(row0 + mt * 16 + r) * DMODEL + col] =
                    acc[mt][nt][r] + bv;
    }
}

// ---------------------------------------------------------------------------
// MFMA flash attention v6 — wave-private LDS slices, ZERO main-loop barriers.
//
// r0-r4 post-mortem: every barrier-synced variant sits at ~1130+ cy per
// 64-key unit (all pipes <=30%); the invariant is the per-chunk
// __syncthreads = vmcnt(0) drain phase-lock. r4 showed direct global->VGPR
// is compiler-hostile (load serialization, VGPR=56). v6 keeps
// global_load_lds staging but makes every staged byte WAVE-PRIVATE:
//   wave w processes keys {w*32 + 128*t}; per iter it stages its own
//   K-slice [32key][64hd] (4 DMA) + V-slice [64d][32tok] (4 DMA) into a
//   private 16 KB double-buffer. No other wave touches those bytes ->
//   no s_barrier. Self-sync via counted s_waitcnt vmcnt(8): issue 8 DMA
//   for t+1, wait until only those 8 remain -> buffer t complete. Loads
//   stay in flight across the whole compute phase (T3/T4), waves free-run
//   out of phase (T5 setprio pays). LDS 64 KB -> 2 blocks/CU, 8 waves
//   (HK-style: free-running 8 waves/CU suffice when pipelined).
// K LDS: proven 3-bit XOR chunk swizzle (frag()). V LDS: 2-bit XOR slot
// swizzle, balanced bank classes. P fully in-register (permuted k-slots).
// Epilogue: r2's proven 4-way cross-wave reduction.
// ---------------------------------------------------------------------------
__global__ __launch_bounds__(256, 2) void attn_mfma_kernel(
    const ushort* __restrict__ Qb, const ushort* __restrict__ Kb,
    const ushort* __restrict__ Vt, ushort* __restrict__ attn_out)
{
    // per-wave 8192 ushorts: buf b at wave*8192 + b*4096 (K 2048 | V 2048)
    __shared__ __align__(16) ushort lds[32768];   // 64 KB

    const int tid  = threadIdx.x;
    const int wave = tid >> 6;
    const int lane = tid & 63;
    const int quad = lane >> 4;
    const int l16  = lane & 15;
    const int h    = blockIdx.y;
    const int i0   = blockIdx.x * 64;

    // Q fragments: all 4 q-tiles register-resident (B-operand: col=l16)
    bf16x8 qf[4][2];
    #pragma unroll
    for (int jt = 0; jt < 4; ++jt) {
        const ushort* qb = Qb + (size_t)(i0 + jt * 16 + l16) * DMODEL + h * HDIM;
        qf[jt][0] = *(const bf16x8*)(qb + quad * 8);
        qf[jt][1] = *(const bf16x8*)(qb + 32 + quad * 8);
    }

    bf16x8 ones;
    #pragma unroll
    for (int i = 0; i < 8; ++i) ones[i] = (short)0x3F80;   // bf16 1.0

    floatx4 O[4][4] = {};    // [q-tile][d-tile], partial over this wave's keys
    floatx4 Ol[4]   = {};    // [q-tile] partial row-sums

    ushort* wls = lds + wave * 8192;                 // private region

    // K staging source (3-bit XOR chunk pre-swizzle, rows = keys)
    const int lrow8 = lane >> 3;                     // 0..7
    const int csw8  = ((lane & 7) ^ lrow8) * 8;
    const ushort* gK = Kb + (size_t)(wave * 32 + lrow8) * DMODEL + h * HDIM + csw8;

    // V staging source (2-bit XOR slot pre-swizzle, rows = d)
    const int vrow4 = lane >> 2;                     // 0..15 (d within p-group)
    const int vslot = (lane & 3) ^ (vrow4 & 3);
    const ushort* gV = Vt + (size_t)(h * HDIM + vrow4) * TOKENS + wave * 32 + vslot * 8;

    // V read offsets (loop-invariant): per nt row, two b64 at permuted slots
    // tokens quad*4+0..3 -> slot quad>>1 ; tokens 16+quad*4+0..3 -> slot 2+(quad>>1)
    const int vx = l16 & 3;                          // row XOR key (row&3 = l16&3)
    const int vo0 = (((quad >> 1)    ) ^ vx) * 8 + (quad & 1) * 4;
    const int vo1 = ((2 + (quad >> 1)) ^ vx) * 8 + (quad & 1) * 4;

    // prologue: stage t=0 into buffer 0 (8 DMA outstanding)
    #pragma unroll
    for (int p = 0; p < 4; ++p)
        gl2lds16(gK + (size_t)p * 8 * DMODEL, wls + p * 512);
    #pragma unroll
    for (int p = 0; p < 4; ++p)
        gl2lds16(gV + (size_t)p * 16 * TOKENS, wls + 2048 + p * 512);

    for (int t = 0; t < TOKENS / 128; ++t) {
        const int cur = t & 1;
        const ushort* Kc = wls + cur * 4096;
        const ushort* Vc = Kc + 2048;

        if (t < TOKENS / 128 - 1) {
            // issue next-iter DMA into the spare private buffer
            ushort* Kn = wls + (1 - cur) * 4096;
            const size_t jn = (size_t)(t + 1) * 128;
            #pragma unroll
            for (int p = 0; p < 4; ++p)
                gl2lds16(gK + (jn + p * 8) * DMODEL, Kn + p * 512);
            #pragma unroll
            for (int p = 0; p < 4; ++p)
                gl2lds16(gV + (size_t)p * 16 * TOKENS + jn, Kn + 2048 + p * 512);
            // wait: of the 16 outstanding, the oldest 8 (buffer t) are done
            asm volatile("s_waitcnt vmcnt(8)" ::: "memory");
        } else {
            asm volatile("s_waitcnt vmcnt(0)" ::: "memory");
        }
        __builtin_amdgcn_sched_barrier(0);

        // ---- all 12 LDS reads up front ----
        bf16x8 af[2][2];
        #pragma unroll
        for (int kt2 = 0; kt2 < 2; ++kt2)
            #pragma unroll
            for (int kh = 0; kh < 2; ++kh)
                af[kt2][kh] = frag(Kc, kt2 * 16 + l16, kh * 4 + quad);

        bf16x8 vf[4];
        #pragma unroll
        for (int nt = 0; nt < 4; ++nt) {
            const ushort* vb = Vc + (nt * 16 + l16) * 32;
            union { bf16x8 v; uint2 d[2]; } vu;
            vu.d[0] = *(const uint2*)(vb + vo0);
            vu.d[1] = *(const uint2*)(vb + vo1);
            vf[nt] = vu.v;
        }

        // ---- QK^T (log2-domain scores) ----
        floatx4 Sv[4][2];
        __builtin_amdgcn_s_setprio(1);
        #pragma unroll
        for (int jt = 0; jt < 4; ++jt)
            #pragma unroll
            for (int kt2 = 0; kt2 < 2; ++kt2) {
                floatx4 s = {0.f, 0.f, 0.f, 0.f};
                s = __builtin_amdgcn_mfma_f32_16x16x32_bf16(af[kt2][0], qf[jt][0], s, 0, 0, 0);
                s = __builtin_amdgcn_mfma_f32_16x16x32_bf16(af[kt2][1], qf[jt][1], s, 0, 0, 0);
                Sv[jt][kt2] = s;
            }
        __builtin_amdgcn_s_setprio(0);

        // ---- p = 2^s, pack in-register; l += P*1 ----
        bf16x8 pa[4];
        #pragma unroll
        for (int jt = 0; jt < 4; ++jt) {
            union { bf16x8 v; unsigned u[4]; } pu;
            #pragma unroll
            for (int kt2 = 0; kt2 < 2; ++kt2) {
                const float p0 = __builtin_amdgcn_exp2f(Sv[jt][kt2][0]);
                const float p1 = __builtin_amdgcn_exp2f(Sv[jt][kt2][1]);
                const float p2 = __builtin_amdgcn_exp2f(Sv[jt][kt2][2]);
                const float p3 = __builtin_amdgcn_exp2f(Sv[jt][kt2][3]);
                pu.u[kt2 * 2]     = cvt_pk_bf16(p0, p1);
                pu.u[kt2 * 2 + 1] = cvt_pk_bf16(p2, p3);
            }
            pa[jt] = pu.v;
            Ol[jt] = __builtin_amdgcn_mfma_f32_16x16x32_bf16(pa[jt], ones, Ol[jt], 0, 0, 0);
        }

        // ---- O += P * V ----
        __builtin_amdgcn_s_setprio(1);
        #pragma unroll
        for (int jt = 0; jt < 4; ++jt)
            #pragma unroll
            for (int nt = 0; nt < 4; ++nt)
                O[jt][nt] = __builtin_amdgcn_mfma_f32_16x16x32_bf16(
                    pa[jt], vf[nt], O[jt][nt], 0, 0, 0);
        __builtin_amdgcn_s_setprio(0);
    }

    // ---- cross-wave reduction + store (r2-proven 4-way epilogue) ----
    __syncthreads();                       // all compute done, LDS reusable
    float* Of  = (float*)lds;              // 3 regions of [64][66] f32
    float* Olf = ((float*)lds) + 3 * 64 * 66;   // 3 x [64] f32
    if (wave != 0) {
        const int rg = (wave - 1) * 64 * 66;
        #pragma unroll
        for (int jt = 0; jt < 4; ++jt) {
            #pragma unroll
            for (int nt = 0; nt < 4; ++nt)
                #pragma unroll
                for (int r = 0; r < 4; ++r)
                    Of[rg + (jt * 16 + quad * 4 + r) * 66 + nt * 16 + l16] = O[jt][nt][r];
            if (l16 == 0) {
                #pragma unroll
                for (int r = 0; r < 4; ++r)
                    Olf[(wave - 1) * 64 + jt * 16 + quad * 4 + r] = Ol[jt][r];
            }
        }
    }
    __syncthreads();
    if (wave == 0) {
        #pragma unroll
        for (int jt = 0; jt < 4; ++jt) {
            const int qr = jt * 16 + quad * 4;
            float linv[4];
            #pragma unroll
            for (int r = 0; r < 4; ++r) {
                const float l = Ol[jt][r] + Olf[qr + r] + Olf[64 + qr + r]
                              + Olf[128 + qr + r];
                linv[r] = __builtin_amdgcn_rcpf(l);
            }
            #pragma unroll
            for (int nt = 0; nt < 4; ++nt) {
                const int d = h * HDIM + nt * 16 + l16;
                #pragma unroll
                for (int r = 0; r < 4; ++r) {
                    const float o = O[jt][nt][r]
                        + Of[(qr + r) * 66 + nt * 16 + l16]
                        + Of[64 * 66 + (qr + r) * 66 + nt * 16 + l16]
                        + Of[2 * 64 * 66 + (qr + r) * 66 + nt * 16 + l16];
                    attn_out[(size_t)(i0 + qr + r) * DMODEL + d] = f2bf(o * linv[r]);
                }
            }
        }
    }
}

// ---------------------------------------------------------------------------
extern "C" void kernel_launch(void* const* d_in, const int* in_sizes, int n_in,
                              void* d_out, int out_size, void* d_ws, size_t ws_size,
                              hipStream_t stream)
{
    const float* x     = (const float*)d_in[0];
    const float* Wqkv  = (const float*)d_in[1];
    const float* Wproj = (const float*)d_in[2];
    const float* bproj = (const float*)d_in[3];
    float* out = (float*)d_out;

    ushort* Xb     = (ushort*)d_ws;                          // [4096][768]
    ushort* WqkvT  = Xb    + (size_t)TOKENS * DMODEL;        // [2304][768]
    ushort* WprojT = WqkvT + (size_t)QKV_N * DMODEL;         // [768][768]
    ushort* Qb     = WprojT + (size_t)DMODEL * DMODEL;       // [4096][768]
    ushort* Kb     = Qb    + (size_t)TOKENS * DMODEL;        // [4096][768]
    ushort* Vt     = Kb    + (size_t)TOKENS * DMODEL;        // [768][4096]
    ushort* attn   = Vt    + (size_t)TOKENS * DMODEL;        // [4096][768]

    cvt_bf16_kernel<<<dim3(TOKENS * DMODEL / 4 / 256), 256, 0, stream>>>(
        x, Xb, TOKENS * DMODEL / 4);
    transpose_cvt_kernel<<<dim3(QKV_N / 32, DMODEL / 32), 256, 0, stream>>>(
        Wqkv, WqkvT, DMODEL, QKV_N);
    transpose_cvt_kernel<<<dim3(DMODEL / 32, DMODEL / 32), 256, 0, stream>>>(
        Wproj, WprojT, DMODEL, DMODEL);

    gemm_qkv_mfma<<<dim3(QKV_N / 128, TOKENS / 128), 256, 0, stream>>>(
        Xb, WqkvT, Qb, Kb, Vt);

    attn_mfma_kernel<<<dim3(TOKENS / 64, NHEADS), 256, 0, stream>>>(
        Qb, Kb, Vt, attn);

    gemm_proj_mfma<<<dim3(DMODEL / 64, TOKENS / 128), 256, 0, stream>>>(
        attn, WprojT, bproj, out);
}

// Round 6
// 202.226 us; speedup vs baseline: 1.9121x; 1.0301x over previous
//
#include <hip/hip_runtime.h>
#include <math.h>

#define TOKENS 4096
#define DMODEL 768
#define NHEADS 12
#define HDIM   64
#define QKV_N  2304          // 3*DMODEL
#define ATTN_SCALE 0.125f    // HDIM^-0.5
// fold log2(e) into Q so softmax uses v_exp_f32 (2^x) directly
#define QSCALE_LOG2E (0.125f * 1.44269504088896340736f)

typedef __attribute__((ext_vector_type(8))) short bf16x8;   // 8 bf16 = 4 VGPRs
typedef __attribute__((ext_vector_type(4))) float floatx4;

__device__ __forceinline__ ushort f2bf(float f) {
    union { float f; unsigned u; } cv; cv.f = f;
    unsigned u = cv.u;
    u += 0x7fffu + ((u >> 16) & 1u);   // round-to-nearest-even
    return (ushort)(u >> 16);
}

// pack two fp32 -> two bf16 (RNE) in one dword via v_cvt_pk_bf16_f32
__device__ __forceinline__ unsigned cvt_pk_bf16(float a, float b) {
    unsigned r;
    asm("v_cvt_pk_bf16_f32 %0, %1, %2" : "=v"(r) : "v"(a), "v"(b));
    return r;
}

// async 16B global->LDS (lane i lands at ldsbase + i*16)
__device__ __forceinline__ void gl2lds16(const ushort* g, ushort* l) {
    __builtin_amdgcn_global_load_lds(
        (const __attribute__((address_space(1))) void*)g,
        (__attribute__((address_space(3))) void*)l, 16, 0, 0);
}

// fragment read (64-ushort rows): logical chunk c of row r at phys (c ^ (r&7))
__device__ __forceinline__ bf16x8 frag(const ushort* ls, int row, int chunk) {
    return *(const bf16x8*)(ls + row * 64 + ((chunk ^ (row & 7)) * 8));
}

// ---------------------------------------------------------------------------
// fp32 -> bf16 elementwise (x)
// ---------------------------------------------------------------------------
__global__ __launch_bounds__(256) void cvt_bf16_kernel(
    const float* __restrict__ in, ushort* __restrict__ out, int n4)
{
    const int i = blockIdx.x * 256 + threadIdx.x;
    if (i < n4) {
        const float4 v = ((const float4*)in)[i];
        ushort4 h;
        h.x = f2bf(v.x); h.y = f2bf(v.y); h.z = f2bf(v.z); h.w = f2bf(v.w);
        ((ushort4*)out)[i] = h;
    }
}

// ---------------------------------------------------------------------------
// fp32 [R][C] -> bf16 [C][R] transpose-convert (weights -> B^T operand layout)
// ---------------------------------------------------------------------------
__global__ __launch_bounds__(256) void transpose_cvt_kernel(
    const float* __restrict__ in, ushort* __restrict__ out, int R, int C)
{
    __shared__ ushort tile[32][33];
    const int tx  = threadIdx.x & 31;
    const int ty8 = threadIdx.x >> 5;           // 0..7
    const int c0 = blockIdx.x * 32;
    const int r0 = blockIdx.y * 32;
    #pragma unroll
    for (int p = 0; p < 4; ++p) {
        const int r = ty8 + p * 8;
        tile[r][tx] = f2bf(in[(size_t)(r0 + r) * C + c0 + tx]);
    }
    __syncthreads();
    #pragma unroll
    for (int p = 0; p < 4; ++p) {
        const int c = ty8 + p * 8;
        out[(size_t)(c0 + c) * R + r0 + tx] = tile[tx][c];
    }
}

// ---------------------------------------------------------------------------
// MFMA GEMM body (m97 recipe): 128 x (NT*32) tile, BK=64, 4 waves 2x2.
// ---------------------------------------------------------------------------
template<int NT>
__device__ __forceinline__ void gemm_body_async(
    const ushort* __restrict__ A, const ushort* __restrict__ Bt, int K,
    int m0, int n0, floatx4 acc[4][NT], ushort* ls)
{
    ushort* lsA = ls;
    ushort* lsB = ls + 8192;

    const int tid  = threadIdx.x;
    const int lane = tid & 63;
    const int wave = tid >> 6;
    const int wm = wave >> 1, wn = wave & 1;
    const int quad = lane >> 4, l16 = lane & 15;

    const int lrow = lane >> 3;          // 0..7
    const int csw  = ((lane & 7) ^ lrow) * 8;   // swizzled global chunk (ushorts)

    const ushort* gA = A  + (size_t)(m0 + wave * 32 + lrow) * K + csw;
    const ushort* gB = Bt + (size_t)(n0 + wave * NT * 8 + lrow) * K + csw;
    ushort* lA = lsA + (wave * 32) * 64;
    ushort* lB = lsB + (wave * NT * 8) * 64;

    for (int k0 = 0; k0 < K; k0 += 64) {
        __syncthreads();
        #pragma unroll
        for (int p = 0; p < 4; ++p)
            gl2lds16(gA + (size_t)p * 8 * K + k0, lA + p * 8 * 64);
        #pragma unroll
        for (int p = 0; p < NT; ++p)
            gl2lds16(gB + (size_t)p * 8 * K + k0, lB + p * 8 * 64);
        __syncthreads();

        #pragma unroll
        for (int ks = 0; ks < 2; ++ks) {
            bf16x8 af[4], bfr[NT];
            #pragma unroll
            for (int mt = 0; mt < 4; ++mt)
                af[mt] = frag(lsA, wm * 64 + mt * 16 + l16, ks * 4 + quad);
            #pragma unroll
            for (int nt = 0; nt < NT; ++nt)
                bfr[nt] = frag(lsB, wn * NT * 16 + nt * 16 + l16, ks * 4 + quad);
            #pragma unroll
            for (int mt = 0; mt < 4; ++mt)
                #pragma unroll
                for (int nt = 0; nt < NT; ++nt)
                    acc[mt][nt] = __builtin_amdgcn_mfma_f32_16x16x32_bf16(
                        af[mt], bfr[nt], acc[mt][nt], 0, 0, 0);
        }
    }
}

// ---------------------------------------------------------------------------
// qkv GEMM: 128x128 tiles. Epilogue re-tiles through LDS (stride 136).
// ---------------------------------------------------------------------------
__global__ __launch_bounds__(256) void gemm_qkv_mfma(
    const ushort* __restrict__ Xb, const ushort* __restrict__ Wt,
    ushort* __restrict__ Qb, ushort* __restrict__ Kb, ushort* __restrict__ Vt)
{
    __shared__ __align__(16) ushort ls[16384];   // 32 KB: GEMM tiles + retile
    const int m0 = blockIdx.y * 128;
    const int n0 = blockIdx.x * 128;

    floatx4 acc[4][4] = {};
    gemm_body_async<4>(Xb, Wt, DMODEL, m0, n0, acc, ls);

    const int tid  = threadIdx.x;
    const int lane = tid & 63;
    const int wave = tid >> 6;
    const int wm = wave >> 1, wn = wave & 1;
    const int quad = lane >> 4, l16 = lane & 15;

    if (n0 < 2 * DMODEL) {
        // ---- Q or K: two passes over 64-row halves ----
        const float scale = (n0 < DMODEL) ? QSCALE_LOG2E : 1.0f;
        ushort* outp = (n0 < DMODEL) ? Qb : Kb;
        const int colg = (n0 < DMODEL) ? n0 : n0 - DMODEL;
        #pragma unroll
        for (int p = 0; p < 2; ++p) {
            __syncthreads();
            if (wm == p) {
                #pragma unroll
                for (int mt = 0; mt < 4; ++mt)
                    #pragma unroll
                    for (int nt = 0; nt < 4; ++nt) {
                        const int row = mt * 16 + quad * 4;
                        const int col = wn * 64 + nt * 16 + l16;
                        #pragma unroll
                        for (int r = 0; r < 4; ++r)
                            ls[(row + r) * 136 + col] = f2bf(acc[mt][nt][r] * scale);
                    }
            }
            __syncthreads();
            #pragma unroll
            for (int p2 = 0; p2 < 4; ++p2) {
                const int row = (tid >> 4) + p2 * 16;
                const int c8  = (tid & 15) * 8;
                *(uint4*)(outp + (size_t)(m0 + p * 64 + row) * DMODEL + colg + c8) =
                    *(const uint4*)(ls + row * 136 + c8);
            }
        }
    } else {
        // ---- V transposed: two passes over 64-hd halves ----
        const int hd0 = n0 - 2 * DMODEL;
        #pragma unroll
        for (int p = 0; p < 2; ++p) {
            __syncthreads();
            if (wn == p) {
                #pragma unroll
                for (int mt = 0; mt < 4; ++mt)
                    #pragma unroll
                    for (int nt = 0; nt < 4; ++nt) {
                        const int hd  = nt * 16 + l16;
                        const int tok = wm * 64 + mt * 16 + quad * 4;
                        #pragma unroll
                        for (int r = 0; r < 4; ++r)
                            ls[hd * 136 + tok + r] = f2bf(acc[mt][nt][r]);
                    }
            }
            __syncthreads();
            #pragma unroll
            for (int p2 = 0; p2 < 4; ++p2) {
                const int row = (tid >> 4) + p2 * 16;    // local hd
                const int c8  = (tid & 15) * 8;          // token chunk
                *(uint4*)(Vt + (size_t)(hd0 + p * 64 + row) * TOKENS + m0 + c8) =
                    *(const uint4*)(ls + row * 136 + c8);
            }
        }
    }
}

// ---------------------------------------------------------------------------
// proj GEMM: 128x64 tiles (grid 384), direct fp32 stores (full 64B sectors).
// ---------------------------------------------------------------------------
__global__ __launch_bounds__(256) void gemm_proj_mfma(
    const ushort* __restrict__ Ab, const ushort* __restrict__ Wt,
    const float* __restrict__ bias, float* __restrict__ out)
{
    __shared__ __align__(16) ushort ls[12288];   // 16 KB A + 8 KB B
    const int m0 = blockIdx.y * 128;
    const int n0 = blockIdx.x * 64;

    floatx4 acc[4][2] = {};
    gemm_body_async<2>(Ab, Wt, DMODEL, m0, n0, acc, ls);

    const int lane = threadIdx.x & 63;
    const int wave = threadIdx.x >> 6;
    const int wm = wave >> 1, wn = wave & 1;
    const int quad = lane >> 4, l16 = lane & 15;
    const int row0 = m0 + wm * 64 + quad * 4;
    const int col0 = n0 + wn * 32;

    #pragma unroll
    for (int nt = 0; nt < 2; ++nt) {
        const int col = col0 + nt * 16 + l16;
        const float bv = bias[col];
        #pragma unroll
        for (int mt = 0; mt < 4; ++mt)
            #pragma unroll
            for (int r = 0; r < 4; ++r)
                out[(size_t)(row0 + mt * 16 + r) * DMODEL + col] =
                    acc[mt][nt][r] + bv;
    }
}

// ---------------------------------------------------------------------------
// MFMA flash attention v7 — barrier-free wave-private, 12 waves/CU flat.
//
// r5 post-mortem: barrier-free worked (82.7us, best) but 64KB blocks -> only
// 2 blocks/CU + tail (occupancy 16%, ~60% latency-idle with 2 waves/SIMD).
// v7 keeps the exact r5 dataflow but resizes for occupancy:
//   - 64-token chunks; wave owns 16 keys/chunk: K-slice [16key][64hd]=2KB
//     (double-buffered), V-slice [64d][16tok]=2KB (4-slot ring, slot=t&3)
//     -> 12KB/wave, 48KB main-loop; epilogue union 51.5KB/block
//     -> 3 blocks/CU resident = exactly the 3 blocks/CU of work
//     -> 12 waves/CU (3/SIMD), ZERO tail.
//   - 16-key chunks half-fill PV k-slots: P packs across an even/odd iter
//     PAIR (low half <- even chunk, high half <- odd), PV+Ol fire once per
//     pair reading the two live V slots. Total MFMA/exp2 work unchanged.
//   - V rows are 32B -> banks rotate naturally: b64 reads hit 4 accesses/
//     bank (structural minimum) with NO swizzle. K keeps the proven 3-bit
//     XOR chunk swizzle.
//   - counted vmcnt(4) self-sync + sched_barrier(0), setprio on MFMA.
// ---------------------------------------------------------------------------
__global__ __launch_bounds__(256, 3) void attn_mfma_kernel(
    const ushort* __restrict__ Qb, const ushort* __restrict__ Kb,
    const ushort* __restrict__ Vt, ushort* __restrict__ attn_out)
{
    // main loop: 4 waves x 6144 ushorts (K0,K1 @0,1024; V0..V3 @2048+s*1024)
    // epilogue:  3 x [64][66] f32 + 192 f32 = 12864 floats = 25728 ushorts
    __shared__ __align__(16) ushort lds[25728];   // 51.5 KB

    const int tid  = threadIdx.x;
    const int wave = tid >> 6;
    const int lane = tid & 63;
    const int quad = lane >> 4;
    const int l16  = lane & 15;
    const int h    = blockIdx.y;
    const int i0   = blockIdx.x * 64;

    // Q fragments: all 4 q-tiles register-resident (B-operand: col=l16)
    bf16x8 qf[4][2];
    #pragma unroll
    for (int jt = 0; jt < 4; ++jt) {
        const ushort* qb = Qb + (size_t)(i0 + jt * 16 + l16) * DMODEL + h * HDIM;
        qf[jt][0] = *(const bf16x8*)(qb + quad * 8);
        qf[jt][1] = *(const bf16x8*)(qb + 32 + quad * 8);
    }

    bf16x8 ones;
    #pragma unroll
    for (int i = 0; i < 8; ++i) ones[i] = (short)0x3F80;   // bf16 1.0

    floatx4 O[4][4] = {};    // [q-tile][d-tile], partial over this wave's keys
    floatx4 Ol[4]   = {};    // [q-tile] partial row-sums

    ushort* wls = lds + wave * 6144;                 // private region

    // K staging source (3-bit XOR chunk pre-swizzle; wave's key = t*64+wave*16+row)
    const int lrow8 = lane >> 3;                     // 0..7
    const int csw8  = ((lane & 7) ^ lrow8) * 8;
    const ushort* gK0 = Kb + (size_t)(wave * 16 + lrow8) * DMODEL + h * HDIM + csw8;
    const ushort* gK1 = gK0 + (size_t)8 * DMODEL;

    // V staging source (linear; lane -> d=lane>>1, tok-half=lane&1)
    const ushort* gV0 = Vt + (size_t)(h * HDIM + (lane >> 1)) * TOKENS
                           + wave * 16 + (lane & 1) * 8;
    const ushort* gV1 = gV0 + (size_t)32 * TOKENS;

    // persistent P operand, packed across an even/odd chunk pair
    union { bf16x8 v; unsigned u[4]; } pa[4];

    // prologue: stage t=0 (K -> buf0, V -> slot0); 4 DMA outstanding
    gl2lds16(gK0, wls);
    gl2lds16(gK1, wls + 512);
    gl2lds16(gV0, wls + 2048);
    gl2lds16(gV1, wls + 2048 + 512);

    for (int u = 0; u < 32; ++u) {                   // pair u: t0=2u, t1=2u+1
        const int s0 = (u & 1) << 1;                 // V slot of t0 (0 or 2)
        ushort* Kc0 = wls;
        ushort* Kc1 = wls + 1024;
        ushort* V0  = wls + 2048 + s0 * 1024;
        ushort* V1  = wls + 2048 + (s0 + 1) * 1024;
        ushort* Vn  = wls + 2048 + ((s0 + 2) & 3) * 1024;

        // ======== t0 = 2u (even): prefetch t1, QK on Kc0 -> pa low half ====
        {
            const size_t t1 = (size_t)(2 * u + 1) * 64;
            gl2lds16(gK0 + t1 * DMODEL, Kc1);
            gl2lds16(gK1 + t1 * DMODEL, Kc1 + 512);
            gl2lds16(gV0 + t1, V1);
            gl2lds16(gV1 + t1, V1 + 512);
        }
        asm volatile("s_waitcnt vmcnt(4)" ::: "memory");   // t0's 4 DMA done
        __builtin_amdgcn_sched_barrier(0);

        {
            const bf16x8 a0 = frag(Kc0, l16, quad);
            const bf16x8 a1 = frag(Kc0, l16, 4 + quad);
            __builtin_amdgcn_s_setprio(1);
            #pragma unroll
            for (int jt = 0; jt < 4; ++jt) {
                floatx4 s = {0.f, 0.f, 0.f, 0.f};
                s = __builtin_amdgcn_mfma_f32_16x16x32_bf16(a0, qf[jt][0], s, 0, 0, 0);
                s = __builtin_amdgcn_mfma_f32_16x16x32_bf16(a1, qf[jt][1], s, 0, 0, 0);
                pa[jt].u[0] = cvt_pk_bf16(__builtin_amdgcn_exp2f(s[0]),
                                          __builtin_amdgcn_exp2f(s[1]));
                pa[jt].u[1] = cvt_pk_bf16(__builtin_amdgcn_exp2f(s[2]),
                                          __builtin_amdgcn_exp2f(s[3]));
            }
            __builtin_amdgcn_s_setprio(0);
        }

        // ======== t1 = 2u+1 (odd): prefetch next t0, QK on Kc1 -> pa high,
        //          then PV + Ol over the 32-key pair ========================
        if (u < 31) {
            const size_t t2 = (size_t)(2 * u + 2) * 64;
            gl2lds16(gK0 + t2 * DMODEL, Kc0);
            gl2lds16(gK1 + t2 * DMODEL, Kc0 + 512);
            gl2lds16(gV0 + t2, Vn);
            gl2lds16(gV1 + t2, Vn + 512);
            asm volatile("s_waitcnt vmcnt(4)" ::: "memory");  // t1's 4 DMA done
        } else {
            asm volatile("s_waitcnt vmcnt(0)" ::: "memory");
        }
        __builtin_amdgcn_sched_barrier(0);

        {
            const bf16x8 a0 = frag(Kc1, l16, quad);
            const bf16x8 a1 = frag(Kc1, l16, 4 + quad);
            __builtin_amdgcn_s_setprio(1);
            #pragma unroll
            for (int jt = 0; jt < 4; ++jt) {
                floatx4 s = {0.f, 0.f, 0.f, 0.f};
                s = __builtin_amdgcn_mfma_f32_16x16x32_bf16(a0, qf[jt][0], s, 0, 0, 0);
                s = __builtin_amdgcn_mfma_f32_16x16x32_bf16(a1, qf[jt][1], s, 0, 0, 0);
                pa[jt].u[2] = cvt_pk_bf16(__builtin_amdgcn_exp2f(s[0]),
                                          __builtin_amdgcn_exp2f(s[1]));
                pa[jt].u[3] = cvt_pk_bf16(__builtin_amdgcn_exp2f(s[2]),
                                          __builtin_amdgcn_exp2f(s[3]));
            }
            __builtin_amdgcn_s_setprio(0);
        }

        __builtin_amdgcn_s_setprio(1);
        #pragma unroll
        for (int nt = 0; nt < 4; ++nt) {
            const int ro = (nt * 16 + l16) * 16 + quad * 4;   // 32B rows, tok quad*4
            union { bf16x8 v; uint2 d[2]; } vu;
            vu.d[0] = *(const uint2*)(V0 + ro);   // even-chunk tokens (k-slots 0-3)
            vu.d[1] = *(const uint2*)(V1 + ro);   // odd-chunk tokens  (k-slots 4-7)
            #pragma unroll
            for (int jt = 0; jt < 4; ++jt)
                O[jt][nt] = __builtin_amdgcn_mfma_f32_16x16x32_bf16(
                    pa[jt].v, vu.v, O[jt][nt], 0, 0, 0);
        }
        #pragma unroll
        for (int jt = 0; jt < 4; ++jt)
            Ol[jt] = __builtin_amdgcn_mfma_f32_16x16x32_bf16(
                pa[jt].v, ones, Ol[jt], 0, 0, 0);
        __builtin_amdgcn_s_setprio(0);
    }

    // ---- cross-wave reduction + store (r5-proven 4-way epilogue) ----
    __syncthreads();                       // all compute done, LDS reusable
    float* Of  = (float*)lds;              // 3 regions of [64][66] f32
    float* Olf = ((float*)lds) + 3 * 64 * 66;   // 3 x [64] f32
    if (wave != 0) {
        const int rg = (wave - 1) * 64 * 66;
        #pragma unroll
        for (int jt = 0; jt < 4; ++jt) {
            #pragma unroll
            for (int nt = 0; nt < 4; ++nt)
                #pragma unroll
                for (int r = 0; r < 4; ++r)
                    Of[rg + (jt * 16 + quad * 4 + r) * 66 + nt * 16 + l16] = O[jt][nt][r];
            if (l16 == 0) {
                #pragma unroll
                for (int r = 0; r < 4; ++r)
                    Olf[(wave - 1) * 64 + jt * 16 + quad * 4 + r] = Ol[jt][r];
            }
        }
    }
    __syncthreads();
    if (wave == 0) {
        #pragma unroll
        for (int jt = 0; jt < 4; ++jt) {
            const int qr = jt * 16 + quad * 4;
            float linv[4];
            #pragma unroll
            for (int r = 0; r < 4; ++r) {
                const float l = Ol[jt][r] + Olf[qr + r] + Olf[64 + qr + r]
                              + Olf[128 + qr + r];
                linv[r] = __builtin_amdgcn_rcpf(l);
            }
            #pragma unroll
            for (int nt = 0; nt < 4; ++nt) {
                const int d = h * HDIM + nt * 16 + l16;
                #pragma unroll
                for (int r = 0; r < 4; ++r) {
                    const float o = O[jt][nt][r]
                        + Of[(qr + r) * 66 + nt * 16 + l16]
                        + Of[64 * 66 + (qr + r) * 66 + nt * 16 + l16]
                        + Of[2 * 64 * 66 + (qr + r) * 66 + nt * 16 + l16];
                    attn_out[(size_t)(i0 + qr + r) * DMODEL + d] = f2bf(o * linv[r]);
                }
            }
        }
    }
}

// ---------------------------------------------------------------------------
extern "C" void kernel_launch(void* const* d_in, const int* in_sizes, int n_in,
                              void* d_out, int out_size, void* d_ws, size_t ws_size,
                              hipStream_t stream)
{
    const float* x     = (const float*)d_in[0];
    const float* Wqkv  = (const float*)d_in[1];
    const float* Wproj = (const float*)d_in[2];
    const float* bproj = (const float*)d_in[3];
    float* out = (float*)d_out;

    ushort* Xb     = (ushort*)d_ws;                          // [4096][768]
    ushort* WqkvT  = Xb    + (size_t)TOKENS * DMODEL;        // [2304][768]
    ushort* WprojT = WqkvT + (size_t)QKV_N * DMODEL;         // [768][768]
    ushort* Qb     = WprojT + (size_t)DMODEL * DMODEL;       // [4096][768]
    ushort* Kb     = Qb    + (size_t)TOKENS * DMODEL;        // [4096][768]
    ushort* Vt     = Kb    + (size_t)TOKENS * DMODEL;        // [768][4096]
    ushort* attn   = Vt    + (size_t)TOKENS * DMODEL;        // [4096][768]

    cvt_bf16_kernel<<<dim3(TOKENS * DMODEL / 4 / 256), 256, 0, stream>>>(
        x, Xb, TOKENS * DMODEL / 4);
    transpose_cvt_kernel<<<dim3(QKV_N / 32, DMODEL / 32), 256, 0, stream>>>(
        Wqkv, WqkvT, DMODEL, QKV_N);
    transpose_cvt_kernel<<<dim3(DMODEL / 32, DMODEL / 32), 256, 0, stream>>>(
        Wproj, WprojT, DMODEL, DMODEL);

    gemm_qkv_mfma<<<dim3(QKV_N / 128, TOKENS / 128), 256, 0, stream>>>(
        Xb, WqkvT, Qb, Kb, Vt);

    attn_mfma_kernel<<<dim3(TOKENS / 64, NHEADS), 256, 0, stream>>>(
        Qb, Kb, Vt, attn);

    gemm_proj_mfma<<<dim3(DMODEL / 64, TOKENS / 128), 256, 0, stream>>>(
        attn, WprojT, bproj, out);
}